// Round 1
// baseline (340.407 us; speedup 1.0000x reference)
//
#include <hip/hip_runtime.h>

// DendralNeuron: out[b,d] = min( min_f(x[b,f]-Wmin[d,f]), min_f(Wmax[d,f]-x[b,f]) )
// VALU/LDS-bound "min-GEMM" (tropical). R4 changes vs R3:
//  (a) register tile 4x2 -> 4x4 (block tile 64x64): ds_read_b128 per triple
//      0.25 -> 0.1875, LDS-pipe cycles -25% (it, not VALU, is the ceiling);
//  (b) double-buffered LDS: 1 barrier/chunk instead of 2;
//  (c) init kernel grid fixed (was writing 4x past out buffer).
// Inner math unchanged: v_pk_add_f32 (packed sub) + v_min3/v_max3,
// 2 VALU insts per (b,d,f) = ISA floor.

constexpr int F_DIM = 784;
constexpr int BM = 64;
constexpr int BN = 64;
constexpr int BK = 16;
constexpr int LSTR = BK + 4;          // 20 floats: 16B-aligned rows, spreads banks
constexpr int NCHUNK = F_DIM / BK;    // 49
constexpr int ZSPLIT = 7;             // F-split: 7 chunks per z-slice
constexpr int CPZ = NCHUNK / ZSPLIT;  // 7

typedef float f4v __attribute__((ext_vector_type(4)));
typedef float f2v __attribute__((ext_vector_type(2)));

__global__ __launch_bounds__(256, 4)
void dendral_init_kernel(float* __restrict__ out) {
  const int i = blockIdx.x * 256 + threadIdx.x;
  const float inf = __builtin_inff();
  f4v v = {inf, inf, inf, inf};
  ((f4v*)out)[i] = v;
}

__device__ inline void atomic_min_float(float* addr, float v) {
  if (v >= 0.0f) atomicMin((int*)addr, __float_as_int(v));
  else           atomicMax((unsigned int*)addr, __float_as_uint(v));
}

__global__ __launch_bounds__(256, 4)
void dendral_min_kernel(const float* __restrict__ x,
                        const float* __restrict__ wmin,
                        const float* __restrict__ wmax,
                        float* __restrict__ out, int D) {
  __shared__ float lx[2][BM * LSTR];    // x tile    [64][20] x2 buf
  __shared__ float lwn[2][BN * LSTR];   // wmin tile [64][20] x2 buf
  __shared__ float lwx[2][BN * LSTR];   // wmax tile [64][20] x2 buf

  const int t  = threadIdx.x;
  const int tx = t & 15;              // d-group: cols tx + 16c, c=0..3
  const int ty = t >> 4;              // b-group: rows ty + 16r, r=0..3
  const int b0 = blockIdx.x * BM;
  const int d0 = blockIdx.y * BN;
  const int c0 = blockIdx.z * CPZ;
  const int c1 = c0 + CPZ;

  // Staging maps: x tile 64x16 = 256 float4 (1/thread);
  // wmin+wmax tiles 2 x 64x16 = 512 float4 (2/thread, wave-uniform split).
  const int xr = t >> 2;              // 0..63
  const int xc = (t & 3) << 2;        // 0,4,8,12
  const int wt = t >> 7;              // 0 -> wmin (waves 0,1), 1 -> wmax (2,3)
  const int wr = (t & 127) >> 1;      // 0..63
  const int wc = (t & 1) << 3;        // 0 or 8 (thread stages 8 floats)

  const float* xg = x + (size_t)(b0 + xr) * F_DIM + xc;
  const float* wg = (wt ? wmax : wmin) + (size_t)(d0 + wr) * F_DIM + wc;
  float* lds_x = &lx[0][xr * LSTR + xc];
  float* lds_w = (wt ? &lwx[0][0] : &lwn[0][0]) + wr * LSTR + wc;
  constexpr int BUFSTRIDE_X = BM * LSTR;   // floats per buffer
  constexpr int BUFSTRIDE_W = BN * LSTR;

  // Prefetch + stage first chunk of this z-slice into buffer 0.
  f4v px  = *(const f4v*)(xg + c0 * BK);
  f4v pw0 = *(const f4v*)(wg + c0 * BK);
  f4v pw1 = *(const f4v*)(wg + c0 * BK + 4);
  *(f4v*)(lds_x) = px;
  *(f4v*)(lds_w) = pw0;
  *(f4v*)(lds_w + 4) = pw1;
  __syncthreads();

  float l1[4][4], mx[4][4];
#pragma unroll
  for (int r = 0; r < 4; ++r)
#pragma unroll
    for (int c = 0; c < 4; ++c) {
      l1[r][c] = __builtin_inff();
      mx[r][c] = -__builtin_inff();
    }

  int cur = 0;
  for (int kc = c0; kc < c1; ++kc) {
    const bool more = (kc + 1 < c1);
    if (more) {                       // register prefetch of next chunk
      px  = *(const f4v*)(xg + (kc + 1) * BK);
      pw0 = *(const f4v*)(wg + (kc + 1) * BK);
      pw1 = *(const f4v*)(wg + (kc + 1) * BK + 4);
    }

    const float* lxb = &lx[cur][ty * LSTR];
    const float* lnb = &lwn[cur][tx * LSTR];
    const float* lwb = &lwx[cur][tx * LSTR];
#pragma unroll
    for (int f = 0; f < BK; f += 4) {
      f4v xv[4], nv[4], wv[4];
#pragma unroll
      for (int r = 0; r < 4; ++r)
        xv[r] = *(const f4v*)&lxb[r * 16 * LSTR + f];
#pragma unroll
      for (int c = 0; c < 4; ++c) {
        nv[c] = *(const f4v*)&lnb[c * 16 * LSTR + f];
        wv[c] = *(const f4v*)&lwb[c * 16 * LSTR + f];
      }
#pragma unroll
      for (int r = 0; r < 4; ++r)
#pragma unroll
        for (int c = 0; c < 4; ++c) {
          // L1 path: min_f(x - wmin); subs as v2f32 -> v_pk_add_f32 (neg)
          f2v a_lo = xv[r].xy - nv[c].xy;
          f2v a_hi = xv[r].zw - nv[c].zw;
          l1[r][c] = fminf(l1[r][c], fminf(a_lo.x, a_lo.y));  // v_min3
          l1[r][c] = fminf(l1[r][c], fminf(a_hi.x, a_hi.y));
          // L2 path: min_f(wmax - x) == -max_f(x - wmax)
          f2v u_lo = xv[r].xy - wv[c].xy;
          f2v u_hi = xv[r].zw - wv[c].zw;
          mx[r][c] = fmaxf(mx[r][c], fmaxf(u_lo.x, u_lo.y));  // v_max3
          mx[r][c] = fmaxf(mx[r][c], fmaxf(u_hi.x, u_hi.y));
        }
    }

    if (more) {                       // stage next chunk into the other buffer
      const int nxt = cur ^ 1;
      *(f4v*)(lds_x + nxt * BUFSTRIDE_X) = px;
      *(f4v*)(lds_w + nxt * BUFSTRIDE_W) = pw0;
      *(f4v*)(lds_w + nxt * BUFSTRIDE_W + 4) = pw1;
      cur = nxt;
    }
    __syncthreads();                  // single barrier per chunk
  }

  // Combine this z-slice's partial into out via device-scope atomic min.
#pragma unroll
  for (int r = 0; r < 4; ++r)
#pragma unroll
    for (int c = 0; c < 4; ++c) {
      const int b = b0 + ty + 16 * r;
      const int d = d0 + tx + 16 * c;
      atomic_min_float(&out[(size_t)b * D + d], fminf(l1[r][c], -mx[r][c]));
    }
}

extern "C" void kernel_launch(void* const* d_in, const int* in_sizes, int n_in,
                              void* d_out, int out_size, void* d_ws, size_t ws_size,
                              hipStream_t stream) {
  const float* x    = (const float*)d_in[0];
  const float* wmin = (const float*)d_in[1];
  const float* wmax = (const float*)d_in[2];
  float* out = (float*)d_out;
  const int B = in_sizes[0] / (F_DIM * 4);  // bytes -> rows? see below
  (void)B;
  // in_sizes are in bytes in this harness convention used previously:
  // previous revision computed B = in_sizes[0] / F_DIM with float counts.
  // Keep identical arithmetic to the verified kernel:
  const int Bn = in_sizes[0] / F_DIM;   // 1024 (element-count convention)
  const int D  = in_sizes[1] / F_DIM;   // 512

  // init: out_size bytes / 16 bytes per float4 / 256 threads
  dendral_init_kernel<<<out_size / (256 * 16), 256, 0, stream>>>(out);

  dim3 grid(Bn / BM, D / BN, ZSPLIT);   // 16 x 8 x 7 = 896 blocks
  dendral_min_kernel<<<grid, 256, 0, stream>>>(x, wmin, wmax, out, D);
  (void)n_in; (void)d_ws; (void)ws_size;
}

// Round 4
// 96.573 us; speedup vs baseline: 3.5249x; 3.5249x over previous
//
#include <hip/hip_runtime.h>

// DendralNeuron: out[b,d] = min( min_f(x[b,f]-Wmin[d,f]), min_f(Wmax[d,f]-x[b,f]) )
// VALU/LDS-bound "min-GEMM" (tropical). R7 = R5 with the occupancy pin spelled
// via __launch_bounds__(256, 2) instead of amdgpu_waves_per_eu(4,4) (two
// container failures in a row; the exact-bounds attribute is the only exotic
// ingredient, and the standard spelling achieves the same fix).
// Changes vs R4 (which spilled):
//  (a) MERGED accumulator: min(min_f(x-wn), min_f(wx-x)) = min_f min(x-wn, wx-x)
//      -> one acc[4][4] instead of l1+mx (32 -> 16 VGPRs), same VALU count
//      (4 pk-subs + 4 v_min3 per (r,c) per 4 features = 2 insts/triple, ISA floor);
//  (b) __launch_bounds__(256, 2): R4's (256,4) = min 4 waves/EU = 64-VGPR cap
//      -> accumulators spilled to scratch in the hot loop (FETCH 437MB +
//      WRITE 828MB scratch traffic, 294us, VALUBusy 13%). Min 2 waves/EU
//      gives a 256-VGPR budget; actual use ~100-130 -> runtime occupancy
//      still 4 waves/EU, but no squeeze-to-64 spills;
//  (c) inner loop restructured (nv/wv outer, xv per-row) to cut peak lives;
//  (d) init grid computed from B*D (out_size is an element count; R4 under-
//      filled 3/4 of out and passed only by luck against the poison pattern).

constexpr int F_DIM = 784;
constexpr int BM = 64;
constexpr int BN = 64;
constexpr int BK = 16;
constexpr int LSTR = BK + 4;          // 20 floats: 16B-aligned rows, spreads banks
constexpr int NCHUNK = F_DIM / BK;    // 49
constexpr int ZSPLIT = 7;             // F-split: 7 chunks per z-slice
constexpr int CPZ = NCHUNK / ZSPLIT;  // 7

typedef float f4v __attribute__((ext_vector_type(4)));
typedef float f2v __attribute__((ext_vector_type(2)));

__global__ __launch_bounds__(256, 4)
void dendral_init_kernel(float* __restrict__ out) {
  const int i = blockIdx.x * 256 + threadIdx.x;
  const float inf = __builtin_inff();
  f4v v = {inf, inf, inf, inf};
  ((f4v*)out)[i] = v;
}

__device__ inline void atomic_min_float(float* addr, float v) {
  if (v >= 0.0f) atomicMin((int*)addr, __float_as_int(v));
  else           atomicMax((unsigned int*)addr, __float_as_uint(v));
}

__global__ __launch_bounds__(256, 2)
void dendral_min_kernel(const float* __restrict__ x,
                        const float* __restrict__ wmin,
                        const float* __restrict__ wmax,
                        float* __restrict__ out, int D) {
  __shared__ float lx[2][BM * LSTR];    // x tile    [64][20] x2 buf
  __shared__ float lwn[2][BN * LSTR];   // wmin tile [64][20] x2 buf
  __shared__ float lwx[2][BN * LSTR];   // wmax tile [64][20] x2 buf

  const int t  = threadIdx.x;
  const int tx = t & 15;              // d-group: cols tx + 16c, c=0..3
  const int ty = t >> 4;              // b-group: rows ty + 16r, r=0..3
  const int b0 = blockIdx.x * BM;
  const int d0 = blockIdx.y * BN;
  const int c0 = blockIdx.z * CPZ;
  const int c1 = c0 + CPZ;

  // Staging maps: x tile 64x16 = 256 float4 (1/thread);
  // wmin+wmax tiles 2 x 64x16 = 512 float4 (2/thread, wave-uniform split).
  const int xr = t >> 2;              // 0..63
  const int xc = (t & 3) << 2;        // 0,4,8,12
  const int wt = t >> 7;              // 0 -> wmin (waves 0,1), 1 -> wmax (2,3)
  const int wr = (t & 127) >> 1;      // 0..63
  const int wc = (t & 1) << 3;        // 0 or 8 (thread stages 8 floats)

  const float* xg = x + (size_t)(b0 + xr) * F_DIM + xc;
  const float* wg = (wt ? wmax : wmin) + (size_t)(d0 + wr) * F_DIM + wc;
  float* lds_x = &lx[0][xr * LSTR + xc];
  float* lds_w = (wt ? &lwx[0][0] : &lwn[0][0]) + wr * LSTR + wc;
  constexpr int BUFSTRIDE_X = BM * LSTR;   // floats per buffer
  constexpr int BUFSTRIDE_W = BN * LSTR;

  // Prefetch + stage first chunk of this z-slice into buffer 0.
  f4v px  = *(const f4v*)(xg + c0 * BK);
  f4v pw0 = *(const f4v*)(wg + c0 * BK);
  f4v pw1 = *(const f4v*)(wg + c0 * BK + 4);
  *(f4v*)(lds_x) = px;
  *(f4v*)(lds_w) = pw0;
  *(f4v*)(lds_w + 4) = pw1;
  __syncthreads();

  float acc[4][4];
#pragma unroll
  for (int r = 0; r < 4; ++r)
#pragma unroll
    for (int c = 0; c < 4; ++c)
      acc[r][c] = __builtin_inff();

  int cur = 0;
  for (int kc = c0; kc < c1; ++kc) {
    const bool more = (kc + 1 < c1);
    if (more) {                       // register prefetch of next chunk
      px  = *(const f4v*)(xg + (kc + 1) * BK);
      pw0 = *(const f4v*)(wg + (kc + 1) * BK);
      pw1 = *(const f4v*)(wg + (kc + 1) * BK + 4);
    }

    const float* lxb = &lx[cur][ty * LSTR];
    const float* lnb = &lwn[cur][tx * LSTR];
    const float* lwb = &lwx[cur][tx * LSTR];
#pragma unroll
    for (int f = 0; f < BK; f += 4) {
      f4v nv[4], wv[4];
#pragma unroll
      for (int c = 0; c < 4; ++c) {
        nv[c] = *(const f4v*)&lnb[c * 16 * LSTR + f];
        wv[c] = *(const f4v*)&lwb[c * 16 * LSTR + f];
      }
#pragma unroll
      for (int r = 0; r < 4; ++r) {
        const f4v xv = *(const f4v*)&lxb[r * 16 * LSTR + f];
#pragma unroll
        for (int c = 0; c < 4; ++c) {
          // d1 = x - wmin (L1 path), d2 = wmax - x (L2 path); packed subs.
          f2v d1lo = xv.xy - nv[c].xy;
          f2v d1hi = xv.zw - nv[c].zw;
          f2v d2lo = wv[c].xy - xv.xy;
          f2v d2hi = wv[c].zw - xv.zw;
          // 8-value min folded into acc via 4 v_min3.
          float t1 = fminf(fminf(d1lo.x, d1lo.y), d1hi.x);
          float t2 = fminf(fminf(d1hi.y, d2lo.x), d2lo.y);
          float t3 = fminf(fminf(d2hi.x, d2hi.y), acc[r][c]);
          acc[r][c] = fminf(fminf(t1, t2), t3);
        }
      }
    }

    if (more) {                       // stage next chunk into the other buffer
      const int nxt = cur ^ 1;
      *(f4v*)(lds_x + nxt * BUFSTRIDE_X) = px;
      *(f4v*)(lds_w + nxt * BUFSTRIDE_W) = pw0;
      *(f4v*)(lds_w + nxt * BUFSTRIDE_W + 4) = pw1;
      cur = nxt;
    }
    __syncthreads();                  // single barrier per chunk
  }

  // Combine this z-slice's partial into out via device-scope atomic min.
#pragma unroll
  for (int r = 0; r < 4; ++r)
#pragma unroll
    for (int c = 0; c < 4; ++c) {
      const int b = b0 + ty + 16 * r;
      const int d = d0 + tx + 16 * c;
      atomic_min_float(&out[(size_t)b * D + d], acc[r][c]);
    }
}

extern "C" void kernel_launch(void* const* d_in, const int* in_sizes, int n_in,
                              void* d_out, int out_size, void* d_ws, size_t ws_size,
                              hipStream_t stream) {
  const float* x    = (const float*)d_in[0];
  const float* wmin = (const float*)d_in[1];
  const float* wmax = (const float*)d_in[2];
  float* out = (float*)d_out;
  const int B = in_sizes[0] / F_DIM;    // 1024 (element-count convention)
  const int D = in_sizes[1] / F_DIM;    // 512

  // Full-coverage init: B*D floats / (4 per thread * 256 threads) blocks.
  dendral_init_kernel<<<(B * D) / 1024, 256, 0, stream>>>(out);

  dim3 grid(B / BM, D / BN, ZSPLIT);    // 16 x 8 x 7 = 896 blocks
  dendral_min_kernel<<<grid, 256, 0, stream>>>(x, wmin, wmax, out, D);
  (void)n_in; (void)d_ws; (void)ws_size; (void)out_size;
}